// Round 1
// baseline (751.589 us; speedup 1.0000x reference)
//
#include <hip/hip_runtime.h>
#include <math.h>

// Problem constants (from reference)
#define T_STEPS 50
#define NS      2048
#define IND     16
#define HID     128
#define GATES   512
#define RR      8
#define KN      32
#define EPSV    1e-10f

// LSTM tiling
#define LROWS   8     // rows per block
#define LTH     256   // threads per block; each thread owns gates t and t+256

__device__ __forceinline__ float sigm(float x) { return 1.0f / (1.0f + __expf(-x)); }

// ---------------------------------------------------------------------------
// Kernel 1: batched LSTM, final hidden state. Rows are independent -> each
// block privately iterates all T=50 steps for its 8 rows. No grid sync.
// ---------------------------------------------------------------------------
__global__ __launch_bounds__(LTH) void lstm_kernel(
    const float* __restrict__ x,     // (T, NS, IND)
    const float* __restrict__ W_ih,  // (GATES, IND)
    const float* __restrict__ W_hh,  // (GATES, HID)
    const float* __restrict__ b_ih,  // (GATES)
    const float* __restrict__ b_hh,  // (GATES)
    float* __restrict__ se)          // (NS, HID) out
{
    __shared__ float sWihT[IND][GATES];    // transposed: conflict-free lane reads
    __shared__ float sh[LROWS][HID];
    __shared__ float scs[LROWS][HID];
    __shared__ float sz[LROWS][GATES];
    __shared__ float sx[LROWS][IND];

    const int t  = threadIdx.x;
    const int n0 = blockIdx.x * LROWS;
    const int j0 = t;
    const int j1 = t + LTH;

    // Stage W_ih transposed
    for (int i = t; i < GATES * IND; i += LTH) {
        int j = i >> 4, k = i & (IND - 1);
        sWihT[k][j] = W_ih[i];
    }
    // h0 = c0 = 0
    for (int i = t; i < LROWS * HID; i += LTH) {
        (&sh[0][0])[i]  = 0.0f;
        (&scs[0][0])[i] = 0.0f;
    }
    const float bias0 = b_ih[j0] + b_hh[j0];
    const float bias1 = b_ih[j1] + b_hh[j1];
    const float4* __restrict__ w0p = (const float4*)(W_hh + j0 * HID);
    const float4* __restrict__ w1p = (const float4*)(W_hh + j1 * HID);
    __syncthreads();

    for (int step = 0; step < T_STEPS; ++step) {
        // stage x_t for the block's 8 rows (128 contiguous floats)
        if (t < LROWS * IND)
            (&sx[0][0])[t] = x[(step * NS + n0) * IND + t];
        __syncthreads();

        float acc0[LROWS], acc1[LROWS];
#pragma unroll
        for (int r = 0; r < LROWS; ++r) { acc0[r] = bias0; acc1[r] = bias1; }

        // x @ W_ih^T part
#pragma unroll
        for (int k = 0; k < IND; ++k) {
            float wv0 = sWihT[k][j0];
            float wv1 = sWihT[k][j1];
#pragma unroll
            for (int r = 0; r < LROWS; ++r) {
                float xv = sx[r][k];
                acc0[r] += xv * wv0;
                acc1[r] += xv * wv1;
            }
        }
        // h @ W_hh^T part: W rows from global (L2-resident), h broadcast from LDS
#pragma unroll 4
        for (int k4 = 0; k4 < HID / 4; ++k4) {
            float4 wa = w0p[k4];
            float4 wb = w1p[k4];
#pragma unroll
            for (int r = 0; r < LROWS; ++r) {
                float4 hv = *(const float4*)&sh[r][k4 * 4];
                acc0[r] += hv.x * wa.x + hv.y * wa.y + hv.z * wa.z + hv.w * wa.w;
                acc1[r] += hv.x * wb.x + hv.y * wb.y + hv.z * wb.z + hv.w * wb.w;
            }
        }
#pragma unroll
        for (int r = 0; r < LROWS; ++r) {
            sz[r][j0] = acc0[r];
            sz[r][j1] = acc1[r];
        }
        __syncthreads();

        // gate activations + state update: 8*128 = 1024 cells, 4 per thread
#pragma unroll
        for (int p = 0; p < (LROWS * HID) / LTH; ++p) {
            int cI  = t + p * LTH;
            int r   = cI >> 7;
            int col = cI & (HID - 1);
            float zi = sz[r][col];
            float zf = sz[r][HID + col];
            float zg = sz[r][2 * HID + col];
            float zo = sz[r][3 * HID + col];
            float cn = sigm(zf) * scs[r][col] + sigm(zi) * tanhf(zg);
            float hn = sigm(zo) * tanhf(cn);
            scs[r][col] = cn;
            sh[r][col]  = hn;
        }
        __syncthreads();
    }

    for (int i = t; i < LROWS * HID; i += LTH)
        se[n0 * HID + i] = (&sh[0][0])[i];
}

// ---------------------------------------------------------------------------
// Kernel 2: per-(r,n) neighbor attention. One wave per pair; 4 pairs/block.
// Stages the 32 gathered neighbor rows in LDS, computes scores, softmax over
// K, weighted sum (rel_rep), and the relation score rscore.
// ---------------------------------------------------------------------------
__global__ __launch_bounds__(256) void attn_kernel(
    const float* __restrict__ se,        // (NS, HID)
    const int*   __restrict__ neighbors, // (RR, NS, KN)
    const float* __restrict__ rel_num,   // (RR, NS)
    const float* __restrict__ w_att,     // (2H + R)
    const float* __restrict__ b_att,     // (1)
    const float* __restrict__ w_rel,     // (H + R)
    const float* __restrict__ b_rel,     // (1)
    float* __restrict__ rel_rep,         // (RR, NS, HID) ws
    float* __restrict__ rscore)          // (RR, NS) ws
{
    __shared__ float snb[4][KN][HID + 4];   // +4 pad: keeps rows 16B-aligned
    __shared__ int   sidx[4][KN];

    const int wid  = threadIdx.x >> 6;
    const int lane = threadIdx.x & 63;
    const int pair = blockIdx.x * 4 + wid;   // = r*NS + n
    const int r    = pair >> 11;             // NS = 2^11
    const int n    = pair & (NS - 1);

    if (lane < KN) sidx[wid][lane] = neighbors[(size_t)pair * KN + lane];
    __syncthreads();

    // stage gathered neighbor embeddings (idx==0 -> zero row)
    const float4* se4 = (const float4*)se;
#pragma unroll
    for (int m = 0; m < (KN * HID / 4) / 64; ++m) {   // 16 iters
        int flat = m * 64 + lane;
        int row  = flat >> 5;
        int c4   = flat & 31;
        int idx  = sidx[wid][row];
        float4 v = make_float4(0.f, 0.f, 0.f, 0.f);
        if (idx != 0) v = se4[(size_t)(idx - 1) * (HID / 4) + c4];
        *((float4*)&snb[wid][row][c4 * 4]) = v;
    }
    __syncthreads();

    // self-dot: sum_h se[n][h] * w_att[H+h]  (all lanes end with full value)
    float p2 = se[n * HID + lane] * w_att[HID + lane]
             + se[n * HID + 64 + lane] * w_att[HID + 64 + lane];
#pragma unroll
    for (int d = 32; d > 0; d >>= 1) p2 += __shfl_xor(p2, d);

    // neighbor scores: lane (k, half) computes half-dot; combine halves
    const int k    = lane & 31;
    const int half = lane >> 5;
    float ps = 0.f;
#pragma unroll
    for (int h4 = 0; h4 < 16; ++h4) {
        float4 v = *(const float4*)&snb[wid][k][half * 64 + h4 * 4];
        float4 w = *(const float4*)&w_att[half * 64 + h4 * 4];
        ps += v.x * w.x + v.y * w.y + v.z * w.z + v.w * w.w;
    }
    ps += __shfl_down(ps, 32);   // lanes 0..31 now hold the full dot

    float s = ps + p2 + w_att[2 * HID + r] + b_att[0];
    // softmax over the 32 k's (lanes 0..31; upper lanes compute garbage,
    // width-32 ops keep it contained, values never consumed)
    float mx = s;
#pragma unroll
    for (int d = 16; d > 0; d >>= 1) mx = fmaxf(mx, __shfl_xor(mx, d, 32));
    float e  = __expf(s - mx);
    float sm = e;
#pragma unroll
    for (int d = 16; d > 0; d >>= 1) sm += __shfl_xor(sm, d, 32);
    float att = e / sm;

    // rel_rep: lane handles h = lane and lane+64
    const float inv = 1.0f / (rel_num[pair] + EPSV);
    float a0 = 0.f, a1 = 0.f;
#pragma unroll
    for (int kk = 0; kk < KN; ++kk) {
        float av = __shfl(att, kk);   // broadcast lane kk's att weight
        a0 += av * snb[wid][kk][lane];
        a1 += av * snb[wid][kk][64 + lane];
    }
    a0 *= inv;
    a1 *= inv;
    rel_rep[(size_t)pair * HID + lane]      = a0;
    rel_rep[(size_t)pair * HID + 64 + lane] = a1;

    float pr = a0 * w_rel[lane] + a1 * w_rel[64 + lane];
#pragma unroll
    for (int d = 32; d > 0; d >>= 1) pr += __shfl_xor(pr, d);
    if (lane == 0) rscore[pair] = pr + w_rel[HID + r] + b_rel[0];
}

// ---------------------------------------------------------------------------
// Kernel 3: per-row softmax over R, weighted mean, residual, final projection.
// One wave per row n.
// ---------------------------------------------------------------------------
__global__ __launch_bounds__(256) void combine_kernel(
    const float* __restrict__ se,       // (NS, HID)
    const float* __restrict__ rel_rep,  // (RR, NS, HID)
    const float* __restrict__ rscore,   // (RR, NS)
    const float* __restrict__ w_fc1,    // (HID)
    const float* __restrict__ b_fc1,    // (1)
    float* __restrict__ out)            // (NS)
{
    const int wid  = threadIdx.x >> 6;
    const int lane = threadIdx.x & 63;
    const int n    = blockIdx.x * 4 + wid;

    float rs[RR];
    float mx = -1e30f;
#pragma unroll
    for (int r = 0; r < RR; ++r) {
        rs[r] = rscore[r * NS + n];
        mx = fmaxf(mx, rs[r]);
    }
    float sm = 0.f;
#pragma unroll
    for (int r = 0; r < RR; ++r) {
        rs[r] = __expf(rs[r] - mx);
        sm += rs[r];
    }
    const float invs = 1.0f / (sm * (float)RR);   // softmax weight * mean(1/R)

    float a0 = 0.f, a1 = 0.f;
#pragma unroll
    for (int r = 0; r < RR; ++r) {
        a0 += rs[r] * rel_rep[((size_t)r * NS + n) * HID + lane];
        a1 += rs[r] * rel_rep[((size_t)r * NS + n) * HID + 64 + lane];
    }
    a0 = a0 * invs + se[n * HID + lane];
    a1 = a1 * invs + se[n * HID + 64 + lane];

    float p = a0 * w_fc1[lane] + a1 * w_fc1[64 + lane];
#pragma unroll
    for (int d = 32; d > 0; d >>= 1) p += __shfl_xor(p, d);
    if (lane == 0) out[n] = p + b_fc1[0];
}

// ---------------------------------------------------------------------------
extern "C" void kernel_launch(void* const* d_in, const int* in_sizes, int n_in,
                              void* d_out, int out_size, void* d_ws, size_t ws_size,
                              hipStream_t stream) {
    const float* x      = (const float*)d_in[0];
    const int*   nbrs   = (const int*)  d_in[1];
    const float* relnum = (const float*)d_in[2];
    const float* W_ih   = (const float*)d_in[3];
    const float* W_hh   = (const float*)d_in[4];
    const float* b_ih   = (const float*)d_in[5];
    const float* b_hh   = (const float*)d_in[6];
    const float* w_att  = (const float*)d_in[7];
    const float* b_att  = (const float*)d_in[8];
    const float* w_rel  = (const float*)d_in[9];
    const float* b_rel  = (const float*)d_in[10];
    const float* w_fc1  = (const float*)d_in[11];
    const float* b_fc1  = (const float*)d_in[12];
    float* out = (float*)d_out;

    // workspace layout (fp32): se (1 MB) | rel_rep (8 MB) | rscore (64 KB)
    float* se      = (float*)d_ws;
    float* rel_rep = se + (size_t)NS * HID;
    float* rscore  = rel_rep + (size_t)RR * NS * HID;

    hipLaunchKernelGGL(lstm_kernel, dim3(NS / LROWS), dim3(LTH), 0, stream,
                       x, W_ih, W_hh, b_ih, b_hh, se);
    hipLaunchKernelGGL(attn_kernel, dim3(RR * NS / 4), dim3(256), 0, stream,
                       se, nbrs, relnum, w_att, b_att, w_rel, b_rel, rel_rep, rscore);
    hipLaunchKernelGGL(combine_kernel, dim3(NS / 4), dim3(256), 0, stream,
                       se, rel_rep, rscore, w_fc1, b_fc1, out);
}

// Round 2
// 147.538 us; speedup vs baseline: 5.0942x; 5.0942x over previous
//
#include <hip/hip_runtime.h>
#include <math.h>

// Problem constants
#define T_STEPS 50
#define NS      2048
#define IND     16
#define HID     128
#define GATES   512
#define RR      8
#define KN      32
#define EPSV    1e-10f

// LSTM MFMA tiling
#define LROWS16 16      // rows per block (one MFMA M-tile)
#define APAD    168     // padded f16 row stride of the A tile (bank spread)
#define LTH     512     // 8 waves

typedef _Float16 f16x8 __attribute__((ext_vector_type(8)));
typedef float    f32x4 __attribute__((ext_vector_type(4)));

__device__ __forceinline__ float sigm(float x)  { return 1.0f / (1.0f + __expf(-x)); }
__device__ __forceinline__ float tanhf_(float x){ return 1.0f - 2.0f / (1.0f + __expf(2.0f * x)); }

// ---------------------------------------------------------------------------
// LSTM via MFMA f16, weights register-resident across all 50 steps.
// Block = 16 rows, 8 waves. Wave w owns gate columns [16w,16w+16) of each of
// the 4 gate groups (i,f,g,o) -> cell update is register-local.
// A (LDS) = [x_t (16) | h_t (128) | zeros (16)] per row, K padded to 160.
// ---------------------------------------------------------------------------
__global__ __launch_bounds__(LTH) void lstm_mfma_kernel(
    const float* __restrict__ x,     // (T, NS, IND)
    const float* __restrict__ W_ih,  // (GATES, IND)
    const float* __restrict__ W_hh,  // (GATES, HID)
    const float* __restrict__ b_ih,  // (GATES)
    const float* __restrict__ b_hh,  // (GATES)
    float* __restrict__ se)          // (NS, HID) out
{
    __shared__ __align__(16) _Float16 sA[LROWS16][APAD];

    const int tid    = threadIdx.x;
    const int w      = tid >> 6;     // wave 0..7
    const int l      = tid & 63;
    const int lane16 = l & 15;
    const int lgrp   = l >> 4;       // 0..3
    const int n0     = blockIdx.x * LROWS16;

    // ---- prologue: W -> f16 B-fragments in registers (static all 50 steps)
    // B[gg][kf]: gate col gi = 128*gg + 16*w + lane16 ; k = kf*32 + lgrp*8 + j
    f16x8 B[4][5];
    float bias[4];
#pragma unroll
    for (int gg = 0; gg < 4; ++gg) {
        const int gi = 128 * gg + 16 * w + lane16;
        bias[gg] = b_ih[gi] + b_hh[gi];
#pragma unroll
        for (int kf = 0; kf < 5; ++kf) {
            const int k0 = kf * 32 + lgrp * 8;
            f16x8 v;
            if (k0 < 16) {                       // x part -> W_ih
                const float* p = W_ih + gi * IND + k0;
#pragma unroll
                for (int j = 0; j < 8; ++j) v[j] = (_Float16)p[j];
            } else if (k0 >= 144) {              // zero pad
#pragma unroll
                for (int j = 0; j < 8; ++j) v[j] = (_Float16)0.0f;
            } else {                             // h part -> W_hh
                const float* p = W_hh + gi * HID + (k0 - 16);
#pragma unroll
                for (int j = 0; j < 8; ++j) v[j] = (_Float16)p[j];
            }
            B[gg][kf] = v;
        }
    }

    // zero sA (h0 = 0, zero K-pad region stays zero forever)
    for (int i = tid; i < LROWS16 * APAD; i += LTH)
        (&sA[0][0])[i] = (_Float16)0.0f;
    __syncthreads();
    // stage x_0
    if (tid < 256)
        sA[tid >> 4][tid & 15] = (_Float16)x[(0 * NS + n0 + (tid >> 4)) * IND + (tid & 15)];

    f32x4 c = {0.f, 0.f, 0.f, 0.f};
    f32x4 h = {0.f, 0.f, 0.f, 0.f};

    for (int step = 0; step < T_STEPS; ++step) {
        __syncthreads();                      // sA holds x_t, h_t

        // prefetch x_{t+1} (hides HBM/L2 latency under MFMA phase)
        float xnext = 0.f;
        if (step + 1 < T_STEPS && tid < 256)
            xnext = x[((step + 1) * NS + n0 + (tid >> 4)) * IND + (tid & 15)];

        // A fragments: lane -> row = lane16, k = kf*32 + lgrp*8 .. +8
        f16x8 A[5];
#pragma unroll
        for (int kf = 0; kf < 5; ++kf)
            A[kf] = *(const f16x8*)&sA[lane16][kf * 32 + lgrp * 8];

        f32x4 zi = {bias[0], bias[0], bias[0], bias[0]};
        f32x4 zf = {bias[1], bias[1], bias[1], bias[1]};
        f32x4 zg = {bias[2], bias[2], bias[2], bias[2]};
        f32x4 zo = {bias[3], bias[3], bias[3], bias[3]};
#pragma unroll
        for (int kf = 0; kf < 5; ++kf) {
            zi = __builtin_amdgcn_mfma_f32_16x16x32_f16(A[kf], B[0][kf], zi, 0, 0, 0);
            zf = __builtin_amdgcn_mfma_f32_16x16x32_f16(A[kf], B[1][kf], zf, 0, 0, 0);
            zg = __builtin_amdgcn_mfma_f32_16x16x32_f16(A[kf], B[2][kf], zg, 0, 0, 0);
            zo = __builtin_amdgcn_mfma_f32_16x16x32_f16(A[kf], B[3][kf], zo, 0, 0, 0);
        }
        __syncthreads();                      // all waves done reading sA

        // cell update, register-local: C layout row = lgrp*4 + r, col = lane16
#pragma unroll
        for (int r = 0; r < 4; ++r) {
            float cn = sigm(zf[r]) * c[r] + sigm(zi[r]) * tanhf_(zg[r]);
            float hn = sigm(zo[r]) * tanhf_(cn);
            c[r] = cn;
            h[r] = hn;
        }

        // write h_{t+1} and x_{t+1} for the next step
        if (step + 1 < T_STEPS) {
            if (tid < 256)
                sA[tid >> 4][tid & 15] = (_Float16)xnext;
#pragma unroll
            for (int r = 0; r < 4; ++r)
                sA[lgrp * 4 + r][16 + 16 * w + lane16] = (_Float16)h[r];
        }
    }

    // store final h (fp32, pre-rounding) as se
#pragma unroll
    for (int r = 0; r < 4; ++r)
        se[(n0 + lgrp * 4 + r) * HID + 16 * w + lane16] = h[r];
}

// ---------------------------------------------------------------------------
// Kernel 2: per-(r,n) neighbor attention (unchanged, ~10 us, L2-resident).
// ---------------------------------------------------------------------------
__global__ __launch_bounds__(256) void attn_kernel(
    const float* __restrict__ se,
    const int*   __restrict__ neighbors,
    const float* __restrict__ rel_num,
    const float* __restrict__ w_att,
    const float* __restrict__ b_att,
    const float* __restrict__ w_rel,
    const float* __restrict__ b_rel,
    float* __restrict__ rel_rep,
    float* __restrict__ rscore)
{
    __shared__ float snb[4][KN][HID + 4];
    __shared__ int   sidx[4][KN];

    const int wid  = threadIdx.x >> 6;
    const int lane = threadIdx.x & 63;
    const int pair = blockIdx.x * 4 + wid;   // = r*NS + n
    const int r    = pair >> 11;
    const int n    = pair & (NS - 1);

    if (lane < KN) sidx[wid][lane] = neighbors[(size_t)pair * KN + lane];
    __syncthreads();

    const float4* se4 = (const float4*)se;
#pragma unroll
    for (int m = 0; m < (KN * HID / 4) / 64; ++m) {
        int flat = m * 64 + lane;
        int row  = flat >> 5;
        int c4   = flat & 31;
        int idx  = sidx[wid][row];
        float4 v = make_float4(0.f, 0.f, 0.f, 0.f);
        if (idx != 0) v = se4[(size_t)(idx - 1) * (HID / 4) + c4];
        *((float4*)&snb[wid][row][c4 * 4]) = v;
    }
    __syncthreads();

    float p2 = se[n * HID + lane] * w_att[HID + lane]
             + se[n * HID + 64 + lane] * w_att[HID + 64 + lane];
#pragma unroll
    for (int d = 32; d > 0; d >>= 1) p2 += __shfl_xor(p2, d);

    const int k    = lane & 31;
    const int half = lane >> 5;
    float ps = 0.f;
#pragma unroll
    for (int h4 = 0; h4 < 16; ++h4) {
        float4 v = *(const float4*)&snb[wid][k][half * 64 + h4 * 4];
        float4 wv = *(const float4*)&w_att[half * 64 + h4 * 4];
        ps += v.x * wv.x + v.y * wv.y + v.z * wv.z + v.w * wv.w;
    }
    ps += __shfl_down(ps, 32);

    float s = ps + p2 + w_att[2 * HID + r] + b_att[0];
    float mx = s;
#pragma unroll
    for (int d = 16; d > 0; d >>= 1) mx = fmaxf(mx, __shfl_xor(mx, d, 32));
    float e  = __expf(s - mx);
    float sm = e;
#pragma unroll
    for (int d = 16; d > 0; d >>= 1) sm += __shfl_xor(sm, d, 32);
    float att = e / sm;

    const float inv = 1.0f / (rel_num[pair] + EPSV);
    float a0 = 0.f, a1 = 0.f;
#pragma unroll
    for (int kk = 0; kk < KN; ++kk) {
        float av = __shfl(att, kk);
        a0 += av * snb[wid][kk][lane];
        a1 += av * snb[wid][kk][64 + lane];
    }
    a0 *= inv;
    a1 *= inv;
    rel_rep[(size_t)pair * HID + lane]      = a0;
    rel_rep[(size_t)pair * HID + 64 + lane] = a1;

    float pr = a0 * w_rel[lane] + a1 * w_rel[64 + lane];
#pragma unroll
    for (int d = 32; d > 0; d >>= 1) pr += __shfl_xor(pr, d);
    if (lane == 0) rscore[pair] = pr + w_rel[HID + r] + b_rel[0];
}

// ---------------------------------------------------------------------------
// Kernel 3: per-row combine (unchanged).
// ---------------------------------------------------------------------------
__global__ __launch_bounds__(256) void combine_kernel(
    const float* __restrict__ se,
    const float* __restrict__ rel_rep,
    const float* __restrict__ rscore,
    const float* __restrict__ w_fc1,
    const float* __restrict__ b_fc1,
    float* __restrict__ out)
{
    const int wid  = threadIdx.x >> 6;
    const int lane = threadIdx.x & 63;
    const int n    = blockIdx.x * 4 + wid;

    float rs[RR];
    float mx = -1e30f;
#pragma unroll
    for (int r = 0; r < RR; ++r) {
        rs[r] = rscore[r * NS + n];
        mx = fmaxf(mx, rs[r]);
    }
    float sm = 0.f;
#pragma unroll
    for (int r = 0; r < RR; ++r) {
        rs[r] = __expf(rs[r] - mx);
        sm += rs[r];
    }
    const float invs = 1.0f / (sm * (float)RR);

    float a0 = 0.f, a1 = 0.f;
#pragma unroll
    for (int r = 0; r < RR; ++r) {
        a0 += rs[r] * rel_rep[((size_t)r * NS + n) * HID + lane];
        a1 += rs[r] * rel_rep[((size_t)r * NS + n) * HID + 64 + lane];
    }
    a0 = a0 * invs + se[n * HID + lane];
    a1 = a1 * invs + se[n * HID + 64 + lane];

    float p = a0 * w_fc1[lane] + a1 * w_fc1[64 + lane];
#pragma unroll
    for (int d = 32; d > 0; d >>= 1) p += __shfl_xor(p, d);
    if (lane == 0) out[n] = p + b_fc1[0];
}

// ---------------------------------------------------------------------------
extern "C" void kernel_launch(void* const* d_in, const int* in_sizes, int n_in,
                              void* d_out, int out_size, void* d_ws, size_t ws_size,
                              hipStream_t stream) {
    const float* x      = (const float*)d_in[0];
    const int*   nbrs   = (const int*)  d_in[1];
    const float* relnum = (const float*)d_in[2];
    const float* W_ih   = (const float*)d_in[3];
    const float* W_hh   = (const float*)d_in[4];
    const float* b_ih   = (const float*)d_in[5];
    const float* b_hh   = (const float*)d_in[6];
    const float* w_att  = (const float*)d_in[7];
    const float* b_att  = (const float*)d_in[8];
    const float* w_rel  = (const float*)d_in[9];
    const float* b_rel  = (const float*)d_in[10];
    const float* w_fc1  = (const float*)d_in[11];
    const float* b_fc1  = (const float*)d_in[12];
    float* out = (float*)d_out;

    float* se      = (float*)d_ws;
    float* rel_rep = se + (size_t)NS * HID;
    float* rscore  = rel_rep + (size_t)RR * NS * HID;

    hipLaunchKernelGGL(lstm_mfma_kernel, dim3(NS / LROWS16), dim3(LTH), 0, stream,
                       x, W_ih, W_hh, b_ih, b_hh, se);
    hipLaunchKernelGGL(attn_kernel, dim3(RR * NS / 4), dim3(256), 0, stream,
                       se, nbrs, relnum, w_att, b_att, w_rel, b_rel, rel_rep, rscore);
    hipLaunchKernelGGL(combine_kernel, dim3(NS / 4), dim3(256), 0, stream,
                       se, rel_rep, rscore, w_fc1, b_fc1, out);
}

// Round 3
// 126.685 us; speedup vs baseline: 5.9327x; 1.1646x over previous
//
#include <hip/hip_runtime.h>
#include <math.h>

// Problem constants
#define T_STEPS 50
#define NS      2048
#define IND     16
#define HID     128
#define GATES   512
#define RR      8
#define KN      32
#define EPSV    1e-10f

// LSTM MFMA tiling
#define LROWS16 16      // rows per block (one MFMA M-tile)
#define APAD    168     // padded f16 row stride of the A tile (bank spread)
#define LTH     512     // 8 waves

typedef _Float16 f16x8 __attribute__((ext_vector_type(8)));
typedef _Float16 f16x4 __attribute__((ext_vector_type(4)));
typedef float    f32x4 __attribute__((ext_vector_type(4)));

__device__ __forceinline__ float sigm(float x)  { return 1.0f / (1.0f + __expf(-x)); }
__device__ __forceinline__ float tanhf_(float x){ return 1.0f - 2.0f / (1.0f + __expf(2.0f * x)); }

// ---------------------------------------------------------------------------
// LSTM via MFMA f16. Weights held in VGPRs across all 50 steps (keep-alive
// asm prevents rematerialization — round-2 showed the compiler re-doing the
// W->f16 prologue every step at VGPR_Count=80). x staged entirely in LDS
// (f16, 25.6 KB) so the step loop touches no global memory. sA double-
// buffered -> one barrier per step.
// ---------------------------------------------------------------------------
__global__ __launch_bounds__(LTH, 2) void lstm_mfma_kernel(
    const float* __restrict__ x,     // (T, NS, IND)
    const float* __restrict__ W_ih,  // (GATES, IND)
    const float* __restrict__ W_hh,  // (GATES, HID)
    const float* __restrict__ b_ih,  // (GATES)
    const float* __restrict__ b_hh,  // (GATES)
    float* __restrict__ se)          // (NS, HID) out
{
    __shared__ __align__(16) _Float16 sA[2][LROWS16][APAD];   // 10.75 KB
    __shared__ __align__(16) _Float16 sX[T_STEPS][256];       // 25.6 KB

    const int tid    = threadIdx.x;
    const int w      = tid >> 6;     // wave 0..7
    const int l      = tid & 63;
    const int lane16 = l & 15;
    const int lgrp   = l >> 4;       // 0..3
    const int n0     = blockIdx.x * LROWS16;

    // ---- prologue: W -> f16 B-fragments in registers (static all 50 steps)
    // B[gg][kf]: gate col gi = 128*gg + 16*w + lane16 ; k = kf*32 + lgrp*8 + j
    f16x8 B[4][5];
    float bias[4];
#pragma unroll
    for (int gg = 0; gg < 4; ++gg) {
        const int gi = 128 * gg + 16 * w + lane16;
        bias[gg] = b_ih[gi] + b_hh[gi];
#pragma unroll
        for (int kf = 0; kf < 5; ++kf) {
            const int k0 = kf * 32 + lgrp * 8;
            f16x8 v;
            if (k0 < 16) {                       // x part -> W_ih
                const float* p = W_ih + gi * IND + k0;
#pragma unroll
                for (int j = 0; j < 8; ++j) v[j] = (_Float16)p[j];
            } else if (k0 >= 144) {              // zero pad
#pragma unroll
                for (int j = 0; j < 8; ++j) v[j] = (_Float16)0.0f;
            } else {                             // h part -> W_hh
                const float* p = W_hh + gi * HID + (k0 - 16);
#pragma unroll
                for (int j = 0; j < 8; ++j) v[j] = (_Float16)p[j];
            }
            B[gg][kf] = v;
        }
    }
    // Opaque to the optimizer: B cannot be rematerialized -> stays in VGPRs.
#pragma unroll
    for (int gg = 0; gg < 4; ++gg)
#pragma unroll
        for (int kf = 0; kf < 5; ++kf)
            asm volatile("" : "+v"(B[gg][kf]));

    // zero both sA buffers (h0 = 0; K-pad cols 144..159 stay zero forever)
    for (int i = tid; i < 2 * LROWS16 * APAD; i += LTH)
        (&sA[0][0][0])[i] = (_Float16)0.0f;

    // stage ALL x for this block's 16 rows, f16 (coalesced, once)
    for (int i = tid; i < T_STEPS * 256; i += LTH) {
        const int t = i >> 8, e = i & 255;
        sX[t][e] = (_Float16)x[((size_t)t * NS + n0) * IND + e];
    }
    __syncthreads();
    if (tid < 256) sA[0][tid >> 4][tid & 15] = sX[0][tid];   // x_0
    __syncthreads();

    f32x4 c = {0.f, 0.f, 0.f, 0.f};
    f32x4 h = {0.f, 0.f, 0.f, 0.f};

    for (int step = 0; step < T_STEPS; ++step) {
        const int cur = step & 1, nxt = cur ^ 1;

        // A fragments: lane -> row = lane16, k = kf*32 + lgrp*8 .. +8
        f16x8 A[5];
#pragma unroll
        for (int kf = 0; kf < 5; ++kf)
            A[kf] = *(const f16x8*)&sA[cur][lane16][kf * 32 + lgrp * 8];

        _Float16 xv = (_Float16)0.0f;
        if (step + 1 < T_STEPS && tid < 256) xv = sX[step + 1][tid];

        f32x4 zi = {bias[0], bias[0], bias[0], bias[0]};
        f32x4 zf = {bias[1], bias[1], bias[1], bias[1]};
        f32x4 zg = {bias[2], bias[2], bias[2], bias[2]};
        f32x4 zo = {bias[3], bias[3], bias[3], bias[3]};
#pragma unroll
        for (int kf = 0; kf < 5; ++kf) {
            zi = __builtin_amdgcn_mfma_f32_16x16x32_f16(A[kf], B[0][kf], zi, 0, 0, 0);
            zf = __builtin_amdgcn_mfma_f32_16x16x32_f16(A[kf], B[1][kf], zf, 0, 0, 0);
            zg = __builtin_amdgcn_mfma_f32_16x16x32_f16(A[kf], B[2][kf], zg, 0, 0, 0);
            zo = __builtin_amdgcn_mfma_f32_16x16x32_f16(A[kf], B[3][kf], zo, 0, 0, 0);
        }

        // cell update, register-local: C layout row = lgrp*4 + r, col = lane16
#pragma unroll
        for (int r = 0; r < 4; ++r) {
            float cn = sigm(zf[r]) * c[r] + sigm(zi[r]) * tanhf_(zg[r]);
            float hn = sigm(zo[r]) * tanhf_(cn);
            c[r] = cn;
            h[r] = hn;
        }

        // write x_{t+1}, h_{t+1} into the OTHER buffer; one barrier per step
        if (step + 1 < T_STEPS) {
            if (tid < 256) sA[nxt][tid >> 4][tid & 15] = xv;
#pragma unroll
            for (int r = 0; r < 4; ++r)
                sA[nxt][lgrp * 4 + r][16 + 16 * w + lane16] = (_Float16)h[r];
        }
        __syncthreads();
    }

    // store final h (fp32 accumulator values) as se
#pragma unroll
    for (int r = 0; r < 4; ++r)
        se[(n0 + lgrp * 4 + r) * HID + 16 * w + lane16] = h[r];
}

// ---------------------------------------------------------------------------
// Kernel 2: per-(r,n) neighbor attention. f16 LDS staging halves LDS
// (66 KB -> 34 KB) -> 2x occupancy.
// ---------------------------------------------------------------------------
__global__ __launch_bounds__(256) void attn_kernel(
    const float* __restrict__ se,
    const int*   __restrict__ neighbors,
    const float* __restrict__ rel_num,
    const float* __restrict__ w_att,
    const float* __restrict__ b_att,
    const float* __restrict__ w_rel,
    const float* __restrict__ b_rel,
    float* __restrict__ rel_rep,
    float* __restrict__ rscore)
{
    __shared__ _Float16 snb[4][KN][HID + 8];
    __shared__ int      sidx[4][KN];

    const int wid  = threadIdx.x >> 6;
    const int lane = threadIdx.x & 63;
    const int pair = blockIdx.x * 4 + wid;   // = r*NS + n
    const int r    = pair >> 11;
    const int n    = pair & (NS - 1);

    if (lane < KN) sidx[wid][lane] = neighbors[(size_t)pair * KN + lane];
    __syncthreads();

    const float4* se4 = (const float4*)se;
#pragma unroll
    for (int m = 0; m < (KN * HID / 4) / 64; ++m) {
        int flat = m * 64 + lane;
        int row  = flat >> 5;
        int c4   = flat & 31;
        int idx  = sidx[wid][row];
        float4 v = make_float4(0.f, 0.f, 0.f, 0.f);
        if (idx != 0) v = se4[(size_t)(idx - 1) * (HID / 4) + c4];
        f16x4 hv = { (_Float16)v.x, (_Float16)v.y, (_Float16)v.z, (_Float16)v.w };
        *((f16x4*)&snb[wid][row][c4 * 4]) = hv;
    }
    __syncthreads();

    float p2 = se[n * HID + lane] * w_att[HID + lane]
             + se[n * HID + 64 + lane] * w_att[HID + 64 + lane];
#pragma unroll
    for (int d = 32; d > 0; d >>= 1) p2 += __shfl_xor(p2, d);

    const int k    = lane & 31;
    const int half = lane >> 5;
    float ps = 0.f;
#pragma unroll
    for (int h4 = 0; h4 < 16; ++h4) {
        f16x4  v  = *(const f16x4*)&snb[wid][k][half * 64 + h4 * 4];
        float4 wv = *(const float4*)&w_att[half * 64 + h4 * 4];
        ps += (float)v[0] * wv.x + (float)v[1] * wv.y
            + (float)v[2] * wv.z + (float)v[3] * wv.w;
    }
    ps += __shfl_down(ps, 32);

    float s = ps + p2 + w_att[2 * HID + r] + b_att[0];
    float mx = s;
#pragma unroll
    for (int d = 16; d > 0; d >>= 1) mx = fmaxf(mx, __shfl_xor(mx, d, 32));
    float e  = __expf(s - mx);
    float sm = e;
#pragma unroll
    for (int d = 16; d > 0; d >>= 1) sm += __shfl_xor(sm, d, 32);
    float att = e / sm;

    const float inv = 1.0f / (rel_num[pair] + EPSV);
    float a0 = 0.f, a1 = 0.f;
#pragma unroll
    for (int kk = 0; kk < KN; ++kk) {
        float av = __shfl(att, kk);
        a0 += av * (float)snb[wid][kk][lane];
        a1 += av * (float)snb[wid][kk][64 + lane];
    }
    a0 *= inv;
    a1 *= inv;
    rel_rep[(size_t)pair * HID + lane]      = a0;
    rel_rep[(size_t)pair * HID + 64 + lane] = a1;

    float pr = a0 * w_rel[lane] + a1 * w_rel[64 + lane];
#pragma unroll
    for (int d = 32; d > 0; d >>= 1) pr += __shfl_xor(pr, d);
    if (lane == 0) rscore[pair] = pr + w_rel[HID + r] + b_rel[0];
}

// ---------------------------------------------------------------------------
// Kernel 3: per-row combine (unchanged).
// ---------------------------------------------------------------------------
__global__ __launch_bounds__(256) void combine_kernel(
    const float* __restrict__ se,
    const float* __restrict__ rel_rep,
    const float* __restrict__ rscore,
    const float* __restrict__ w_fc1,
    const float* __restrict__ b_fc1,
    float* __restrict__ out)
{
    const int wid  = threadIdx.x >> 6;
    const int lane = threadIdx.x & 63;
    const int n    = blockIdx.x * 4 + wid;

    float rs[RR];
    float mx = -1e30f;
#pragma unroll
    for (int r = 0; r < RR; ++r) {
        rs[r] = rscore[r * NS + n];
        mx = fmaxf(mx, rs[r]);
    }
    float sm = 0.f;
#pragma unroll
    for (int r = 0; r < RR; ++r) {
        rs[r] = __expf(rs[r] - mx);
        sm += rs[r];
    }
    const float invs = 1.0f / (sm * (float)RR);

    float a0 = 0.f, a1 = 0.f;
#pragma unroll
    for (int r = 0; r < RR; ++r) {
        a0 += rs[r] * rel_rep[((size_t)r * NS + n) * HID + lane];
        a1 += rs[r] * rel_rep[((size_t)r * NS + n) * HID + 64 + lane];
    }
    a0 = a0 * invs + se[n * HID + lane];
    a1 = a1 * invs + se[n * HID + 64 + lane];

    float p = a0 * w_fc1[lane] + a1 * w_fc1[64 + lane];
#pragma unroll
    for (int d = 32; d > 0; d >>= 1) p += __shfl_xor(p, d);
    if (lane == 0) out[n] = p + b_fc1[0];
}

// ---------------------------------------------------------------------------
extern "C" void kernel_launch(void* const* d_in, const int* in_sizes, int n_in,
                              void* d_out, int out_size, void* d_ws, size_t ws_size,
                              hipStream_t stream) {
    const float* x      = (const float*)d_in[0];
    const int*   nbrs   = (const int*)  d_in[1];
    const float* relnum = (const float*)d_in[2];
    const float* W_ih   = (const float*)d_in[3];
    const float* W_hh   = (const float*)d_in[4];
    const float* b_ih   = (const float*)d_in[5];
    const float* b_hh   = (const float*)d_in[6];
    const float* w_att  = (const float*)d_in[7];
    const float* b_att  = (const float*)d_in[8];
    const float* w_rel  = (const float*)d_in[9];
    const float* b_rel  = (const float*)d_in[10];
    const float* w_fc1  = (const float*)d_in[11];
    const float* b_fc1  = (const float*)d_in[12];
    float* out = (float*)d_out;

    float* se      = (float*)d_ws;
    float* rel_rep = se + (size_t)NS * HID;
    float* rscore  = rel_rep + (size_t)RR * NS * HID;

    hipLaunchKernelGGL(lstm_mfma_kernel, dim3(NS / LROWS16), dim3(LTH), 0, stream,
                       x, W_ih, W_hh, b_ih, b_hh, se);
    hipLaunchKernelGGL(attn_kernel, dim3(RR * NS / 4), dim3(256), 0, stream,
                       se, nbrs, relnum, w_att, b_att, w_rel, b_rel, rel_rep, rscore);
    hipLaunchKernelGGL(combine_kernel, dim3(NS / 4), dim3(256), 0, stream,
                       se, rel_rep, rscore, w_fc1, b_fc1, out);
}

// Round 4
// 102.080 us; speedup vs baseline: 7.3628x; 1.2410x over previous
//
#include <hip/hip_runtime.h>
#include <math.h>

// Problem constants
#define T_STEPS 50
#define NS      2048
#define IND     16
#define HID     128
#define GATES   512
#define RR      8
#define KN      32
#define EPSV    1e-10f

// LSTM MFMA tiling: 256 blocks x 8 rows -> all 256 CUs active.
#define LROWS   8       // real rows per block (MFMA M-tile rows 8..15 = zero)
#define APAD    168     // padded f16 row stride of the A tile (bank spread)
#define LTH     512     // 8 waves; wave w owns gate cols [16w,16w+16) per group

typedef _Float16 f16x8 __attribute__((ext_vector_type(8)));
typedef _Float16 f16x4 __attribute__((ext_vector_type(4)));
typedef float    f32x4 __attribute__((ext_vector_type(4)));

__device__ __forceinline__ float sigm(float x)  { return 1.0f / (1.0f + __expf(-x)); }
__device__ __forceinline__ float tanhf_(float x){ return 1.0f - 2.0f / (1.0f + __expf(2.0f * x)); }

// ---------------------------------------------------------------------------
// LSTM via MFMA f16. 8 real rows in a 16-row M-tile (rows 8-15 zero).
// After MFMA, two shfl_xor(32) per gate redistribute C rows 2,3 of each
// lane-group to the upper wave half so ALL 64 lanes compute 2 real cells
// (no dummy-lane transcendentals). Weights in registers across all steps;
// x LDS-staged; double-buffered sA; one barrier per step.
// ---------------------------------------------------------------------------
__global__ __launch_bounds__(LTH, 2) void lstm_mfma_kernel(
    const float* __restrict__ x,     // (T, NS, IND)
    const float* __restrict__ W_ih,  // (GATES, IND)
    const float* __restrict__ W_hh,  // (GATES, HID)
    const float* __restrict__ b_ih,  // (GATES)
    const float* __restrict__ b_hh,  // (GATES)
    float* __restrict__ se)          // (NS, HID) out
{
    __shared__ __align__(16) _Float16 sA[2][16][APAD];           // 10.75 KB
    __shared__ __align__(16) _Float16 sX[T_STEPS][LROWS * IND];  // 12.8 KB

    const int tid    = threadIdx.x;
    const int w      = tid >> 6;       // wave 0..7
    const int l      = tid & 63;
    const int lane16 = l & 15;
    const int lgrp   = l >> 4;         // 0..3 (MFMA fragment row group)
    const int half   = l >> 5;         // 0 lower / 1 upper wave half
    const int lg     = (l >> 4) & 1;   // row-pair group within half
    const int n0     = blockIdx.x * LROWS;

    // ---- prologue: W -> f16 B-fragments in registers (static all 50 steps)
    // B[gg][kf]: gate col gi = 128*gg + 16*w + lane16 ; k = kf*32 + lgrp*8 + j
    f16x8 B[4][5];
    float bias[4];
#pragma unroll
    for (int gg = 0; gg < 4; ++gg) {
        const int gi = 128 * gg + 16 * w + lane16;
        bias[gg] = b_ih[gi] + b_hh[gi];
#pragma unroll
        for (int kf = 0; kf < 5; ++kf) {
            const int k0 = kf * 32 + lgrp * 8;
            f16x8 v;
            if (k0 < 16) {                       // x part -> W_ih
                const float* p = W_ih + gi * IND + k0;
#pragma unroll
                for (int j = 0; j < 8; ++j) v[j] = (_Float16)p[j];
            } else if (k0 >= 144) {              // zero pad
#pragma unroll
                for (int j = 0; j < 8; ++j) v[j] = (_Float16)0.0f;
            } else {                             // h part -> W_hh
                const float* p = W_hh + gi * HID + (k0 - 16);
#pragma unroll
                for (int j = 0; j < 8; ++j) v[j] = (_Float16)p[j];
            }
            B[gg][kf] = v;
        }
    }
    // Opaque to the optimizer: B cannot be rematerialized -> stays resident.
#pragma unroll
    for (int gg = 0; gg < 4; ++gg)
#pragma unroll
        for (int kf = 0; kf < 5; ++kf)
            asm volatile("" : "+v"(B[gg][kf]));

    // zero both sA buffers (rows 8-15 and K-pad cols stay zero forever)
    for (int i = tid; i < 2 * 16 * APAD; i += LTH)
        (&sA[0][0][0])[i] = (_Float16)0.0f;

    // stage ALL x for this block's 8 rows, f16 (coalesced, once)
    for (int i = tid; i < T_STEPS * LROWS * IND; i += LTH) {
        const int t = i >> 7, e = i & 127;
        sX[t][e] = (_Float16)x[((size_t)t * NS + n0) * IND + e];
    }
    __syncthreads();
    if (tid < LROWS * IND) sA[0][tid >> 4][tid & 15] = sX[0][tid];   // x_0
    __syncthreads();

    // each lane owns cells (row0, col) and (row0+1, col), col = 16w + lane16
    const int row0 = lg * 4 + half * 2;
    float c0 = 0.f, c1 = 0.f, h0 = 0.f, h1 = 0.f;

    for (int step = 0; step < T_STEPS; ++step) {
        const int cur = step & 1, nxt = cur ^ 1;

        // A fragments: lane -> row = lane16 (rows 8-15 read zeros)
        f16x8 A[5];
#pragma unroll
        for (int kf = 0; kf < 5; ++kf)
            A[kf] = *(const f16x8*)&sA[cur][lane16][kf * 32 + lgrp * 8];

        _Float16 xv = (_Float16)0.0f;
        if (step + 1 < T_STEPS && tid < LROWS * IND) xv = sX[step + 1][tid];

        f32x4 zi = {bias[0], bias[0], bias[0], bias[0]};
        f32x4 zf = {bias[1], bias[1], bias[1], bias[1]};
        f32x4 zg = {bias[2], bias[2], bias[2], bias[2]};
        f32x4 zo = {bias[3], bias[3], bias[3], bias[3]};
#pragma unroll
        for (int kf = 0; kf < 5; ++kf) {
            zi = __builtin_amdgcn_mfma_f32_16x16x32_f16(A[kf], B[0][kf], zi, 0, 0, 0);
            zf = __builtin_amdgcn_mfma_f32_16x16x32_f16(A[kf], B[1][kf], zf, 0, 0, 0);
            zg = __builtin_amdgcn_mfma_f32_16x16x32_f16(A[kf], B[2][kf], zg, 0, 0, 0);
            zo = __builtin_amdgcn_mfma_f32_16x16x32_f16(A[kf], B[3][kf], zo, 0, 0, 0);
        }

        // redistribute: upper half takes partner's C rows 2,3 -> every lane
        // ends with 2 REAL cells (rows row0, row0+1)
        float i2 = __shfl_xor(zi[2], 32), i3 = __shfl_xor(zi[3], 32);
        float f2 = __shfl_xor(zf[2], 32), f3 = __shfl_xor(zf[3], 32);
        float g2 = __shfl_xor(zg[2], 32), g3 = __shfl_xor(zg[3], 32);
        float o2 = __shfl_xor(zo[2], 32), o3 = __shfl_xor(zo[3], 32);
        float vi0 = half ? i2 : zi[0], vi1 = half ? i3 : zi[1];
        float vf0 = half ? f2 : zf[0], vf1 = half ? f3 : zf[1];
        float vg0 = half ? g2 : zg[0], vg1 = half ? g3 : zg[1];
        float vo0 = half ? o2 : zo[0], vo1 = half ? o3 : zo[1];

        c0 = sigm(vf0) * c0 + sigm(vi0) * tanhf_(vg0);
        h0 = sigm(vo0) * tanhf_(c0);
        c1 = sigm(vf1) * c1 + sigm(vi1) * tanhf_(vg1);
        h1 = sigm(vo1) * tanhf_(c1);

        // write x_{t+1}, h_{t+1} into the other buffer; one barrier per step
        if (step + 1 < T_STEPS) {
            if (tid < LROWS * IND) sA[nxt][tid >> 4][tid & 15] = xv;
            sA[nxt][row0][16 + 16 * w + lane16]     = (_Float16)h0;
            sA[nxt][row0 + 1][16 + 16 * w + lane16] = (_Float16)h1;
        }
        __syncthreads();
    }

    se[(n0 + row0) * HID + 16 * w + lane16]     = h0;
    se[(n0 + row0 + 1) * HID + 16 * w + lane16] = h1;
}

// ---------------------------------------------------------------------------
// Kernel 2: per-(r,n) neighbor attention (f16 LDS staging).
// ---------------------------------------------------------------------------
__global__ __launch_bounds__(256) void attn_kernel(
    const float* __restrict__ se,
    const int*   __restrict__ neighbors,
    const float* __restrict__ rel_num,
    const float* __restrict__ w_att,
    const float* __restrict__ b_att,
    const float* __restrict__ w_rel,
    const float* __restrict__ b_rel,
    float* __restrict__ rel_rep,
    float* __restrict__ rscore)
{
    __shared__ _Float16 snb[4][KN][HID + 8];
    __shared__ int      sidx[4][KN];

    const int wid  = threadIdx.x >> 6;
    const int lane = threadIdx.x & 63;
    const int pair = blockIdx.x * 4 + wid;   // = r*NS + n
    const int r    = pair >> 11;
    const int n    = pair & (NS - 1);

    if (lane < KN) sidx[wid][lane] = neighbors[(size_t)pair * KN + lane];
    __syncthreads();

    const float4* se4 = (const float4*)se;
#pragma unroll
    for (int m = 0; m < (KN * HID / 4) / 64; ++m) {
        int flat = m * 64 + lane;
        int row  = flat >> 5;
        int c4   = flat & 31;
        int idx  = sidx[wid][row];
        float4 v = make_float4(0.f, 0.f, 0.f, 0.f);
        if (idx != 0) v = se4[(size_t)(idx - 1) * (HID / 4) + c4];
        f16x4 hv = { (_Float16)v.x, (_Float16)v.y, (_Float16)v.z, (_Float16)v.w };
        *((f16x4*)&snb[wid][row][c4 * 4]) = hv;
    }
    __syncthreads();

    float p2 = se[n * HID + lane] * w_att[HID + lane]
             + se[n * HID + 64 + lane] * w_att[HID + 64 + lane];
#pragma unroll
    for (int d = 32; d > 0; d >>= 1) p2 += __shfl_xor(p2, d);

    const int k    = lane & 31;
    const int half = lane >> 5;
    float ps = 0.f;
#pragma unroll
    for (int h4 = 0; h4 < 16; ++h4) {
        f16x4  v  = *(const f16x4*)&snb[wid][k][half * 64 + h4 * 4];
        float4 wv = *(const float4*)&w_att[half * 64 + h4 * 4];
        ps += (float)v[0] * wv.x + (float)v[1] * wv.y
            + (float)v[2] * wv.z + (float)v[3] * wv.w;
    }
    ps += __shfl_down(ps, 32);

    float s = ps + p2 + w_att[2 * HID + r] + b_att[0];
    float mx = s;
#pragma unroll
    for (int d = 16; d > 0; d >>= 1) mx = fmaxf(mx, __shfl_xor(mx, d, 32));
    float e  = __expf(s - mx);
    float sm = e;
#pragma unroll
    for (int d = 16; d > 0; d >>= 1) sm += __shfl_xor(sm, d, 32);
    float att = e / sm;

    const float inv = 1.0f / (rel_num[pair] + EPSV);
    float a0 = 0.f, a1 = 0.f;
#pragma unroll
    for (int kk = 0; kk < KN; ++kk) {
        float av = __shfl(att, kk);
        a0 += av * (float)snb[wid][kk][lane];
        a1 += av * (float)snb[wid][kk][64 + lane];
    }
    a0 *= inv;
    a1 *= inv;
    rel_rep[(size_t)pair * HID + lane]      = a0;
    rel_rep[(size_t)pair * HID + 64 + lane] = a1;

    float pr = a0 * w_rel[lane] + a1 * w_rel[64 + lane];
#pragma unroll
    for (int d = 32; d > 0; d >>= 1) pr += __shfl_xor(pr, d);
    if (lane == 0) rscore[pair] = pr + w_rel[HID + r] + b_rel[0];
}

// ---------------------------------------------------------------------------
// Kernel 3: per-row combine (unchanged).
// ---------------------------------------------------------------------------
__global__ __launch_bounds__(256) void combine_kernel(
    const float* __restrict__ se,
    const float* __restrict__ rel_rep,
    const float* __restrict__ rscore,
    const float* __restrict__ w_fc1,
    const float* __restrict__ b_fc1,
    float* __restrict__ out)
{
    const int wid  = threadIdx.x >> 6;
    const int lane = threadIdx.x & 63;
    const int n    = blockIdx.x * 4 + wid;

    float rs[RR];
    float mx = -1e30f;
#pragma unroll
    for (int r = 0; r < RR; ++r) {
        rs[r] = rscore[r * NS + n];
        mx = fmaxf(mx, rs[r]);
    }
    float sm = 0.f;
#pragma unroll
    for (int r = 0; r < RR; ++r) {
        rs[r] = __expf(rs[r] - mx);
        sm += rs[r];
    }
    const float invs = 1.0f / (sm * (float)RR);

    float a0 = 0.f, a1 = 0.f;
#pragma unroll
    for (int r = 0; r < RR; ++r) {
        a0 += rs[r] * rel_rep[((size_t)r * NS + n) * HID + lane];
        a1 += rs[r] * rel_rep[((size_t)r * NS + n) * HID + 64 + lane];
    }
    a0 = a0 * invs + se[n * HID + lane];
    a1 = a1 * invs + se[n * HID + 64 + lane];

    float p = a0 * w_fc1[lane] + a1 * w_fc1[64 + lane];
#pragma unroll
    for (int d = 32; d > 0; d >>= 1) p += __shfl_xor(p, d);
    if (lane == 0) out[n] = p + b_fc1[0];
}

// ---------------------------------------------------------------------------
extern "C" void kernel_launch(void* const* d_in, const int* in_sizes, int n_in,
                              void* d_out, int out_size, void* d_ws, size_t ws_size,
                              hipStream_t stream) {
    const float* x      = (const float*)d_in[0];
    const int*   nbrs   = (const int*)  d_in[1];
    const float* relnum = (const float*)d_in[2];
    const float* W_ih   = (const float*)d_in[3];
    const float* W_hh   = (const float*)d_in[4];
    const float* b_ih   = (const float*)d_in[5];
    const float* b_hh   = (const float*)d_in[6];
    const float* w_att  = (const float*)d_in[7];
    const float* b_att  = (const float*)d_in[8];
    const float* w_rel  = (const float*)d_in[9];
    const float* b_rel  = (const float*)d_in[10];
    const float* w_fc1  = (const float*)d_in[11];
    const float* b_fc1  = (const float*)d_in[12];
    float* out = (float*)d_out;

    float* se      = (float*)d_ws;
    float* rel_rep = se + (size_t)NS * HID;
    float* rscore  = rel_rep + (size_t)RR * NS * HID;

    hipLaunchKernelGGL(lstm_mfma_kernel, dim3(NS / LROWS), dim3(LTH), 0, stream,
                       x, W_ih, W_hh, b_ih, b_hh, se);
    hipLaunchKernelGGL(attn_kernel, dim3(RR * NS / 4), dim3(256), 0, stream,
                       se, nbrs, relnum, w_att, b_att, w_rel, b_rel, rel_rep, rscore);
    hipLaunchKernelGGL(combine_kernel, dim3(NS / 4), dim3(256), 0, stream,
                       se, rel_rep, rscore, w_fc1, b_fc1, out);
}